// Round 1
// baseline (330.620 us; speedup 1.0000x reference)
//
#include <hip/hip_runtime.h>
#include <hip/hip_bf16.h>
#include <cstdint>

// LSTM cell: B=8192, I=1024, H=1024.
// gates = [x|h] @ [Wf|Wi|Wc|Wo] + b ; fused elementwise gate combine.
// Strategy: bf16 MFMA GEMM (m97 structure) with per-gate accumulator groups so
// the epilogue is lane-local (no gates matrix materialized).

#define BROWS 8192
#define IH    2048
#define HDIM  1024

typedef __bf16 bf16x8 __attribute__((ext_vector_type(8)));
typedef float  f32x4  __attribute__((ext_vector_type(4)));

// ---------------------------------------------------------------- pack_A
// A_bf16[8192][2048] = concat(input, hidden) cast to bf16. 8 elems/thread.
__global__ void pack_A(const float* __restrict__ x, const float* __restrict__ hs,
                       __bf16* __restrict__ A) {
    size_t t = (size_t)blockIdx.x * 256 + threadIdx.x;
    size_t e = t * 8;                         // element index in [0, 8192*2048)
    int row = (int)(e >> 11);
    int col = (int)(e & 2047);
    const float* src = (col < 1024) ? (x + (size_t)row * 1024 + col)
                                    : (hs + (size_t)row * 1024 + (col - 1024));
    const float4 v0 = ((const float4*)src)[0];
    const float4 v1 = ((const float4*)src)[1];
    bf16x8 r;
    r[0] = (__bf16)v0.x; r[1] = (__bf16)v0.y; r[2] = (__bf16)v0.z; r[3] = (__bf16)v0.w;
    r[4] = (__bf16)v1.x; r[5] = (__bf16)v1.y; r[6] = (__bf16)v1.z; r[7] = (__bf16)v1.w;
    *(bf16x8*)(A + e) = r;
}

// ---------------------------------------------------------------- pack_W
// Wt[g*1024 + n][k] = W_g[k][n], cast to bf16. Tiled 32x32 transpose via LDS.
__global__ void pack_W(const float* __restrict__ Wf, const float* __restrict__ Wi,
                       const float* __restrict__ Wc, const float* __restrict__ Wo,
                       __bf16* __restrict__ Wt) {
    __shared__ float tile[32][33];            // +1 pad: conflict-free column read
    const int g = blockIdx.z;
    const float* W = (g == 0) ? Wf : (g == 1) ? Wi : (g == 2) ? Wc : Wo;
    const int n0 = blockIdx.x * 32;
    const int k0 = blockIdx.y * 32;
    const int tx = threadIdx.x;               // 0..31
    const int ty = threadIdx.y;               // 0..7
#pragma unroll
    for (int i = 0; i < 4; ++i) {
        int k = k0 + ty + i * 8;
        tile[ty + i * 8][tx] = W[(size_t)k * HDIM + n0 + tx];
    }
    __syncthreads();
#pragma unroll
    for (int i = 0; i < 4; ++i) {
        int n = n0 + ty + i * 8;
        Wt[(size_t)(g * HDIM + n) * IH + k0 + tx] = (__bf16)tile[tx][ty + i * 8];
    }
}

// ---------------------------------------------------------------- lstm_gemm
// Block: 256 threads (4 waves). Tile: BM=128 rows x BH=32 h-cols x 4 gates
// (effective 128x128 GEMM tile). BK=64. 16x16x32 bf16 MFMA.
// Wave w: wr=w>>1 picks 64-row half (4 row-tiles), wc=w&1 picks 16-col half.
// acc[gate][rtile] — 64 fp32/lane.
#define BM 128
#define BH 32
#define BK 64

__global__ void lstm_gemm(const __bf16* __restrict__ A,    // [8192][2048]
                          const __bf16* __restrict__ Wt,   // [4096][2048], row g*1024+h
                          const float* __restrict__ cell,  // [8192][1024]
                          const float* __restrict__ bF_, const float* __restrict__ bI_,
                          const float* __restrict__ bC_, const float* __restrict__ bO_,
                          float* __restrict__ out)         // [2][8192][1024]
{
    __shared__ __bf16 As[BM * BK];            // [128][64] row-major
    __shared__ __bf16 Bs[4 * BH * BK];        // [128][64], row = g*32 + hl

    const int tid  = threadIdx.x;
    const int wave = tid >> 6;                // 0..3
    const int lane = tid & 63;
    const int quad = lane >> 4;               // 0..3
    const int l16  = lane & 15;
    const int wr   = wave >> 1;               // 0..1 : row half
    const int wc   = wave & 1;                // 0..1 : col half

    const int m0 = blockIdx.y * BM;
    const int h0 = blockIdx.x * BH;

    // staging lane mapping: 1 KiB per wave-instruction = 8 rows of 128 B
    const int lrow = lane >> 3;               // 0..7
    const int lk   = (lane & 7) * 8;          // element offset, 16 B per lane

    f32x4 acc[4][4] = {};                     // [gate][rtile]

    for (int k0 = 0; k0 < IH; k0 += BK) {
        // ---- stage A tile: 16 chunks of 8 rows; wave w does chunks w*4+i
#pragma unroll
        for (int i = 0; i < 4; ++i) {
            int c = wave * 4 + i;
            int row = c * 8 + lrow;
            const __bf16* gp = A + (size_t)(m0 + row) * IH + k0 + lk;
            __bf16* lp = &As[c * 8 * BK];     // wave-uniform LDS base
            __builtin_amdgcn_global_load_lds(
                (const __attribute__((address_space(1))) unsigned*)gp,
                (__attribute__((address_space(3))) unsigned*)lp, 16, 0, 0);
        }
        // ---- stage B tile: rows rl = g*32+hl
#pragma unroll
        for (int i = 0; i < 4; ++i) {
            int c = wave * 4 + i;
            int rl = c * 8 + lrow;            // 0..127
            int g = rl >> 5, hl = rl & 31;
            const __bf16* gp = Wt + (size_t)(g * HDIM + h0 + hl) * IH + k0 + lk;
            __bf16* lp = &Bs[c * 8 * BK];
            __builtin_amdgcn_global_load_lds(
                (const __attribute__((address_space(1))) unsigned*)gp,
                (__attribute__((address_space(3))) unsigned*)lp, 16, 0, 0);
        }
        __syncthreads();

#pragma unroll
        for (int ki = 0; ki < BK; ki += 32) {
            bf16x8 af[4], bg[4];
#pragma unroll
            for (int r = 0; r < 4; ++r)
                af[r] = *(const bf16x8*)&As[(wr * 64 + r * 16 + l16) * BK + ki + quad * 8];
#pragma unroll
            for (int g = 0; g < 4; ++g)
                bg[g] = *(const bf16x8*)&Bs[(g * 32 + wc * 16 + l16) * BK + ki + quad * 8];
#pragma unroll
            for (int g = 0; g < 4; ++g)
#pragma unroll
                for (int r = 0; r < 4; ++r)
                    acc[g][r] = __builtin_amdgcn_mfma_f32_16x16x32_bf16(
                        af[r], bg[g], acc[g][r], 0, 0, 0);
        }
        __syncthreads();
    }

    // ---- fused epilogue: f,i,c̄,o for (m,h) are lane-local across acc[g]
    const int h = h0 + wc * 16 + l16;
    const float bF = bF_[h], bI = bI_[h], bC = bC_[h], bO = bO_[h];
#pragma unroll
    for (int r = 0; r < 4; ++r) {
#pragma unroll
        for (int reg = 0; reg < 4; ++reg) {
            const int m = m0 + wr * 64 + r * 16 + quad * 4 + reg;
            float pf = acc[0][r][reg] + bF;
            float pi = acc[1][r][reg] + bI;
            float pc = acc[2][r][reg] + bC;
            float po = acc[3][r][reg] + bO;
            float f  = 1.f / (1.f + __expf(-pf));
            float ig = 1.f / (1.f + __expf(-pi));
            float og = 1.f / (1.f + __expf(-po));
            float e2 = __expf(2.f * pc);
            float cd = (e2 - 1.f) / (e2 + 1.f);          // tanh(pc)
            float cp = cell[(size_t)m * HDIM + h];
            float cn = f * cp + ig * cd;
            float ec = __expf(2.f * cn);
            float tc = (ec - 1.f) / (ec + 1.f);          // tanh(cn)
            out[(size_t)m * HDIM + h] = og * tc;                       // new_hidden
            out[(size_t)BROWS * HDIM + (size_t)m * HDIM + h] = cn;     // new_cell
        }
    }
}

// ---------------------------------------------------------------- launch
extern "C" void kernel_launch(void* const* d_in, const int* in_sizes, int n_in,
                              void* d_out, int out_size, void* d_ws, size_t ws_size,
                              hipStream_t stream) {
    const float* x  = (const float*)d_in[0];
    const float* hs = (const float*)d_in[1];
    const float* cs = (const float*)d_in[2];
    const float* Wf = (const float*)d_in[3];
    const float* bF = (const float*)d_in[4];
    const float* Wi = (const float*)d_in[5];
    const float* bI = (const float*)d_in[6];
    const float* Wc = (const float*)d_in[7];
    const float* bC = (const float*)d_in[8];
    const float* Wo = (const float*)d_in[9];
    const float* bO = (const float*)d_in[10];
    float* out = (float*)d_out;

    __bf16* A  = (__bf16*)d_ws;                                   // 32 MiB
    __bf16* Wt = (__bf16*)((char*)d_ws + (size_t)BROWS * IH * 2); // 16 MiB

    pack_A<<<(BROWS * IH / 8) / 256, 256, 0, stream>>>(x, hs, A);
    pack_W<<<dim3(HDIM / 32, IH / 32, 4), dim3(32, 8), 0, stream>>>(Wf, Wi, Wc, Wo, Wt);
    lstm_gemm<<<dim3(HDIM / BH, BROWS / BM), 256, 0, stream>>>(A, Wt, cs, bF, bI, bC, bO, out);
}

// Round 2
// 317.682 us; speedup vs baseline: 1.0407x; 1.0407x over previous
//
#include <hip/hip_runtime.h>
#include <hip/hip_bf16.h>
#include <cstdint>

// LSTM cell: B=8192, I=1024, H=1024.
// gates = [x|h] @ [Wf|Wi|Wc|Wo] + b ; fused elementwise gate combine.
// R2: XOR-swizzled LDS (kills 5e7 bank-conflict cycles of R1's 128B-stride
// layout) + single fused pack kernel with vectorized stores.

#define BROWS 8192
#define IH    2048
#define HDIM  1024

typedef __bf16 bf16x8 __attribute__((ext_vector_type(8)));
typedef float  f32x4  __attribute__((ext_vector_type(4)));

// ---------------------------------------------------------------- pack_fused
// Blocks [0,4096):        A_bf16[8192][2048] = bf16(concat(x,h)), 16 elem/thread
// Blocks [4096,4096+2048): Wt[g*1024+n][k] = bf16(W_g[k][n]), 64x64 LDS transpose
__global__ void pack_fused(const float* __restrict__ x, const float* __restrict__ hs,
                           const float* __restrict__ Wf, const float* __restrict__ Wi,
                           const float* __restrict__ Wc, const float* __restrict__ Wo,
                           __bf16* __restrict__ A, __bf16* __restrict__ Wt) {
    __shared__ float tile[64][65];            // W-transpose tile (+1 pitch)
    const int bb = blockIdx.x;
    if (bb < 4096) {
        // ---- A pack: each thread converts 16 contiguous floats (one half-row seg)
        size_t t = (size_t)bb * 256 + threadIdx.x;
        size_t e = t * 16;                    // 16-aligned => stays in one half
        int row = (int)(e >> 11);
        int col = (int)(e & 2047);
        const float* src = (col < 1024) ? (x + (size_t)row * 1024 + col)
                                        : (hs + (size_t)row * 1024 + (col - 1024));
        float4 v0 = ((const float4*)src)[0];
        float4 v1 = ((const float4*)src)[1];
        float4 v2 = ((const float4*)src)[2];
        float4 v3 = ((const float4*)src)[3];
        bf16x8 r0, r1;
        r0[0]=(__bf16)v0.x; r0[1]=(__bf16)v0.y; r0[2]=(__bf16)v0.z; r0[3]=(__bf16)v0.w;
        r0[4]=(__bf16)v1.x; r0[5]=(__bf16)v1.y; r0[6]=(__bf16)v1.z; r0[7]=(__bf16)v1.w;
        r1[0]=(__bf16)v2.x; r1[1]=(__bf16)v2.y; r1[2]=(__bf16)v2.z; r1[3]=(__bf16)v2.w;
        r1[4]=(__bf16)v3.x; r1[5]=(__bf16)v3.y; r1[6]=(__bf16)v3.z; r1[7]=(__bf16)v3.w;
        *(bf16x8*)(A + e) = r0;
        *(bf16x8*)(A + e + 8) = r1;
    } else {
        // ---- W transpose+cast: 64k x 64n tile
        const int wb = bb - 4096;             // 0..2047
        const int g  = wb & 3;
        const int rest = wb >> 2;             // 0..511
        const int n0 = (rest & 15) * 64;
        const int k0 = (rest >> 4) * 64;
        const float* W = (g == 0) ? Wf : (g == 1) ? Wi : (g == 2) ? Wc : Wo;
        const int tx = threadIdx.x & 63;
        const int ty = threadIdx.x >> 6;      // 0..3
#pragma unroll
        for (int i = 0; i < 16; ++i) {
            int k = ty + i * 4;
            tile[k][tx] = W[(size_t)(k0 + k) * HDIM + n0 + tx];
        }
        __syncthreads();
        const int n  = threadIdx.x >> 2;      // 0..63
        const int kq = threadIdx.x & 3;       // 0..3, 16 k's each
        __bf16* dst = Wt + (size_t)(g * HDIM + n0 + n) * IH + k0 + kq * 16;
#pragma unroll
        for (int s = 0; s < 2; ++s) {
            bf16x8 r;
#pragma unroll
            for (int j = 0; j < 8; ++j) r[j] = (__bf16)tile[kq * 16 + s * 8 + j][n];
            *(bf16x8*)(dst + s * 8) = r;
        }
    }
}

// ---------------------------------------------------------------- lstm_gemm
// Block: 256 threads (4 waves). Tile: BM=128 rows x BH=32 h-cols x 4 gates
// (effective 128x128 GEMM tile). BK=64. 16x16x32 bf16 MFMA.
// LDS layout XOR-swizzle: logical 16B chunk jc of row r lives at physical
// chunk jc^(r&7) -> fragment reads hit all 32 banks, 2 lanes/bank (free).
#define BM 128
#define BH 32
#define BK 64

__global__ void lstm_gemm(const __bf16* __restrict__ A,    // [8192][2048]
                          const __bf16* __restrict__ Wt,   // [4096][2048], row g*1024+h
                          const float* __restrict__ cell,  // [8192][1024]
                          const float* __restrict__ bF_, const float* __restrict__ bI_,
                          const float* __restrict__ bC_, const float* __restrict__ bO_,
                          float* __restrict__ out)         // [2][8192][1024]
{
    __shared__ __bf16 As[BM * BK];            // [128][64], swizzled chunks
    __shared__ __bf16 Bs[4 * BH * BK];        // [128][64], row = g*32 + hl

    const int tid  = threadIdx.x;
    const int wave = tid >> 6;                // 0..3
    const int lane = tid & 63;
    const int quad = lane >> 4;               // 0..3
    const int l16  = lane & 15;
    const int wr   = wave >> 1;               // row half
    const int wc   = wave & 1;                // col half
    const int sw   = l16 & 7;                 // read-side swizzle key (row&7)

    const int m0 = blockIdx.y * BM;
    const int h0 = blockIdx.x * BH;

    // staging: lane l -> LDS phys chunk (l&7) of row (l>>3); fetch the global
    // chunk whose logical index is (l&7)^(lrow&7) so phys holds swizzled data
    const int lrow = lane >> 3;               // 0..7
    const int lk   = (((lane & 7) ^ (lrow & 7)) << 3);  // element offset

    f32x4 acc[4][4] = {};                     // [gate][rtile]

    for (int k0 = 0; k0 < IH; k0 += BK) {
        // ---- stage A tile: 16 chunks of 8 rows; wave w does chunks w*4+i
#pragma unroll
        for (int i = 0; i < 4; ++i) {
            int c = wave * 4 + i;
            int row = c * 8 + lrow;
            const __bf16* gp = A + (size_t)(m0 + row) * IH + k0 + lk;
            __bf16* lp = &As[c * 8 * BK];     // wave-uniform LDS base
            __builtin_amdgcn_global_load_lds(
                (const __attribute__((address_space(1))) unsigned*)gp,
                (__attribute__((address_space(3))) unsigned*)lp, 16, 0, 0);
        }
        // ---- stage B tile: rows rl = g*32+hl
#pragma unroll
        for (int i = 0; i < 4; ++i) {
            int c = wave * 4 + i;
            int rl = c * 8 + lrow;            // 0..127
            int g = rl >> 5, hl = rl & 31;
            const __bf16* gp = Wt + (size_t)(g * HDIM + h0 + hl) * IH + k0 + lk;
            __bf16* lp = &Bs[c * 8 * BK];
            __builtin_amdgcn_global_load_lds(
                (const __attribute__((address_space(1))) unsigned*)gp,
                (__attribute__((address_space(3))) unsigned*)lp, 16, 0, 0);
        }
        __syncthreads();

#pragma unroll
        for (int ki = 0; ki < BK; ki += 32) {
            const int kk = ki >> 3;           // 0 or 4
            const int ch = (kk + quad) ^ sw;  // physical chunk for this lane
            bf16x8 af[4], bg[4];
#pragma unroll
            for (int r = 0; r < 4; ++r) {
                int ra = wr * 64 + r * 16 + l16;
                af[r] = *(const bf16x8*)&As[ra * BK + (ch << 3)];
            }
#pragma unroll
            for (int g = 0; g < 4; ++g) {
                int rb = g * 32 + wc * 16 + l16;
                bg[g] = *(const bf16x8*)&Bs[rb * BK + (ch << 3)];
            }
#pragma unroll
            for (int g = 0; g < 4; ++g)
#pragma unroll
                for (int r = 0; r < 4; ++r)
                    acc[g][r] = __builtin_amdgcn_mfma_f32_16x16x32_bf16(
                        af[r], bg[g], acc[g][r], 0, 0, 0);
        }
        __syncthreads();
    }

    // ---- fused epilogue: f,i,c̄,o for (m,h) are lane-local across acc[g]
    const int h = h0 + wc * 16 + l16;
    const float bF = bF_[h], bI = bI_[h], bC = bC_[h], bO = bO_[h];
#pragma unroll
    for (int r = 0; r < 4; ++r) {
#pragma unroll
        for (int reg = 0; reg < 4; ++reg) {
            const int m = m0 + wr * 64 + r * 16 + quad * 4 + reg;
            float pf = acc[0][r][reg] + bF;
            float pi = acc[1][r][reg] + bI;
            float pc = acc[2][r][reg] + bC;
            float po = acc[3][r][reg] + bO;
            float f  = 1.f / (1.f + __expf(-pf));
            float ig = 1.f / (1.f + __expf(-pi));
            float og = 1.f / (1.f + __expf(-po));
            float e2 = __expf(2.f * pc);
            float cd = (e2 - 1.f) / (e2 + 1.f);          // tanh(pc)
            float cp = cell[(size_t)m * HDIM + h];
            float cn = f * cp + ig * cd;
            float ec = __expf(2.f * cn);
            float tc = (ec - 1.f) / (ec + 1.f);          // tanh(cn)
            out[(size_t)m * HDIM + h] = og * tc;                       // new_hidden
            out[(size_t)BROWS * HDIM + (size_t)m * HDIM + h] = cn;     // new_cell
        }
    }
}

// ---------------------------------------------------------------- launch
extern "C" void kernel_launch(void* const* d_in, const int* in_sizes, int n_in,
                              void* d_out, int out_size, void* d_ws, size_t ws_size,
                              hipStream_t stream) {
    const float* x  = (const float*)d_in[0];
    const float* hs = (const float*)d_in[1];
    const float* cs = (const float*)d_in[2];
    const float* Wf = (const float*)d_in[3];
    const float* bF = (const float*)d_in[4];
    const float* Wi = (const float*)d_in[5];
    const float* bI = (const float*)d_in[6];
    const float* Wc = (const float*)d_in[7];
    const float* bC = (const float*)d_in[8];
    const float* Wo = (const float*)d_in[9];
    const float* bO = (const float*)d_in[10];
    float* out = (float*)d_out;

    __bf16* A  = (__bf16*)d_ws;                                   // 32 MiB
    __bf16* Wt = (__bf16*)((char*)d_ws + (size_t)BROWS * IH * 2); // 16 MiB

    pack_fused<<<4096 + 2048, 256, 0, stream>>>(x, hs, Wf, Wi, Wc, Wo, A, Wt);
    lstm_gemm<<<dim3(HDIM / BH, BROWS / BM), 256, 0, stream>>>(A, Wt, cs, bF, bI, bC, bO, out);
}

// Round 3
// 317.174 us; speedup vs baseline: 1.0424x; 1.0016x over previous
//
#include <hip/hip_runtime.h>
#include <hip/hip_bf16.h>
#include <cstdint>

// LSTM cell: B=8192, I=1024, H=1024.
// gates = [x|h] @ [Wf|Wi|Wc|Wo] + b ; fused elementwise gate combine.
// R3: GEMM identical to R2 (910 TF, 0 bank conflicts). Pack stage rebuilt:
// two lean kernels, no big-LDS occupancy cap, lane-dense access patterns.
// Controlled experiment to decompose the ~166us non-GEMM time.

#define BROWS 8192
#define IH    2048
#define HDIM  1024

typedef __bf16 bf16x4 __attribute__((ext_vector_type(4)));
typedef __bf16 bf16x8 __attribute__((ext_vector_type(8)));
typedef float  f32x4  __attribute__((ext_vector_type(4)));

// ---------------------------------------------------------------- pack_A
// A_bf16[8192][2048] = bf16(concat(x,h)). Lane-dense: each pass, lane i
// loads float4 at i*16B (1KiB/wave/instr), stores bf16x4 (8B). No LDS.
__global__ void pack_A(const float* __restrict__ x, const float* __restrict__ hs,
                       __bf16* __restrict__ A) {
    const int tid = threadIdx.x;
    const size_t base = (size_t)blockIdx.x * 2048;   // floats per block
#pragma unroll
    for (int p = 0; p < 2; ++p) {
        size_t e = base + (size_t)p * 1024 + (size_t)tid * 4;
        int row = (int)(e >> 11);
        int col = (int)(e & 2047);
        const float* src = (col < 1024) ? (x + (size_t)row * 1024 + col)
                                        : (hs + (size_t)row * 1024 + (col - 1024));
        float4 v = *(const float4*)src;
        bf16x4 r;
        r[0] = (__bf16)v.x; r[1] = (__bf16)v.y; r[2] = (__bf16)v.z; r[3] = (__bf16)v.w;
        *(bf16x4*)(A + e) = r;
    }
}

// ---------------------------------------------------------------- pack_W
// Wt[g*1024+n][k] = bf16(W_g[k][n]). 32x32 float LDS tile (4.2KB -> full
// occupancy). Phase1: float4 reads (128B/row-seg). Phase2: column reads at
// 2 lanes/bank (free), stores in 64B-contiguous segments.
__global__ void pack_W(const float* __restrict__ Wf, const float* __restrict__ Wi,
                       const float* __restrict__ Wc, const float* __restrict__ Wo,
                       __bf16* __restrict__ Wt) {
    __shared__ float tile[32][33];
    int b = blockIdx.x;
    const int g = b & 3; b >>= 2;
    const int nt = b & 31;            // 32 n-tiles
    const int kt = b >> 5;            // 64 k-tiles
    const int n0 = nt * 32, k0 = kt * 32;
    const float* W = (g == 0) ? Wf : (g == 1) ? Wi : (g == 2) ? Wc : Wo;
    const int tid = threadIdx.x;
    {   // phase 1: 256 threads x 1 float4 = 32x32 tile
        const int k = tid >> 3, c = tid & 7;
        *(float4*)&tile[k][c * 4] = *(const float4*)&W[(size_t)(k0 + k) * HDIM + n0 + c * 4];
    }
    __syncthreads();
    {   // phase 2: thread -> (n = tid>>3, kq = tid&7), 4 k's each
        const int n = tid >> 3, kq = tid & 7;
        bf16x4 r;
#pragma unroll
        for (int j = 0; j < 4; ++j) r[j] = (__bf16)tile[kq * 4 + j][n];
        *(bf16x4*)&Wt[(size_t)(g * HDIM + n0 + n) * IH + k0 + kq * 4] = r;
    }
}

// ---------------------------------------------------------------- lstm_gemm
// (byte-identical to R2: 128x128 effective tile, BK=64, 16x16x32 bf16 MFMA,
//  XOR-swizzled LDS chunks -> 0 bank conflicts, fused lane-local epilogue)
#define BM 128
#define BH 32
#define BK 64

__global__ void lstm_gemm(const __bf16* __restrict__ A,    // [8192][2048]
                          const __bf16* __restrict__ Wt,   // [4096][2048], row g*1024+h
                          const float* __restrict__ cell,  // [8192][1024]
                          const float* __restrict__ bF_, const float* __restrict__ bI_,
                          const float* __restrict__ bC_, const float* __restrict__ bO_,
                          float* __restrict__ out)         // [2][8192][1024]
{
    __shared__ __bf16 As[BM * BK];            // [128][64], swizzled chunks
    __shared__ __bf16 Bs[4 * BH * BK];        // [128][64], row = g*32 + hl

    const int tid  = threadIdx.x;
    const int wave = tid >> 6;                // 0..3
    const int lane = tid & 63;
    const int quad = lane >> 4;               // 0..3
    const int l16  = lane & 15;
    const int wr   = wave >> 1;               // row half
    const int wc   = wave & 1;                // col half
    const int sw   = l16 & 7;                 // read-side swizzle key (row&7)

    const int m0 = blockIdx.y * BM;
    const int h0 = blockIdx.x * BH;

    const int lrow = lane >> 3;               // 0..7
    const int lk   = (((lane & 7) ^ (lrow & 7)) << 3);  // swizzled element offset

    f32x4 acc[4][4] = {};                     // [gate][rtile]

    for (int k0 = 0; k0 < IH; k0 += BK) {
#pragma unroll
        for (int i = 0; i < 4; ++i) {
            int c = wave * 4 + i;
            int row = c * 8 + lrow;
            const __bf16* gp = A + (size_t)(m0 + row) * IH + k0 + lk;
            __bf16* lp = &As[c * 8 * BK];
            __builtin_amdgcn_global_load_lds(
                (const __attribute__((address_space(1))) unsigned*)gp,
                (__attribute__((address_space(3))) unsigned*)lp, 16, 0, 0);
        }
#pragma unroll
        for (int i = 0; i < 4; ++i) {
            int c = wave * 4 + i;
            int rl = c * 8 + lrow;            // 0..127
            int g = rl >> 5, hl = rl & 31;
            const __bf16* gp = Wt + (size_t)(g * HDIM + h0 + hl) * IH + k0 + lk;
            __bf16* lp = &Bs[c * 8 * BK];
            __builtin_amdgcn_global_load_lds(
                (const __attribute__((address_space(1))) unsigned*)gp,
                (__attribute__((address_space(3))) unsigned*)lp, 16, 0, 0);
        }
        __syncthreads();

#pragma unroll
        for (int ki = 0; ki < BK; ki += 32) {
            const int kk = ki >> 3;           // 0 or 4
            const int ch = (kk + quad) ^ sw;  // physical chunk for this lane
            bf16x8 af[4], bg[4];
#pragma unroll
            for (int r = 0; r < 4; ++r) {
                int ra = wr * 64 + r * 16 + l16;
                af[r] = *(const bf16x8*)&As[ra * BK + (ch << 3)];
            }
#pragma unroll
            for (int g = 0; g < 4; ++g) {
                int rb = g * 32 + wc * 16 + l16;
                bg[g] = *(const bf16x8*)&Bs[rb * BK + (ch << 3)];
            }
#pragma unroll
            for (int g = 0; g < 4; ++g)
#pragma unroll
                for (int r = 0; r < 4; ++r)
                    acc[g][r] = __builtin_amdgcn_mfma_f32_16x16x32_bf16(
                        af[r], bg[g], acc[g][r], 0, 0, 0);
        }
        __syncthreads();
    }

    const int h = h0 + wc * 16 + l16;
    const float bF = bF_[h], bI = bI_[h], bC = bC_[h], bO = bO_[h];
#pragma unroll
    for (int r = 0; r < 4; ++r) {
#pragma unroll
        for (int reg = 0; reg < 4; ++reg) {
            const int m = m0 + wr * 64 + r * 16 + quad * 4 + reg;
            float pf = acc[0][r][reg] + bF;
            float pi = acc[1][r][reg] + bI;
            float pc = acc[2][r][reg] + bC;
            float po = acc[3][r][reg] + bO;
            float f  = 1.f / (1.f + __expf(-pf));
            float ig = 1.f / (1.f + __expf(-pi));
            float og = 1.f / (1.f + __expf(-po));
            float e2 = __expf(2.f * pc);
            float cd = (e2 - 1.f) / (e2 + 1.f);          // tanh(pc)
            float cp = cell[(size_t)m * HDIM + h];
            float cn = f * cp + ig * cd;
            float ec = __expf(2.f * cn);
            float tc = (ec - 1.f) / (ec + 1.f);          // tanh(cn)
            out[(size_t)m * HDIM + h] = og * tc;                       // new_hidden
            out[(size_t)BROWS * HDIM + (size_t)m * HDIM + h] = cn;     // new_cell
        }
    }
}

// ---------------------------------------------------------------- launch
extern "C" void kernel_launch(void* const* d_in, const int* in_sizes, int n_in,
                              void* d_out, int out_size, void* d_ws, size_t ws_size,
                              hipStream_t stream) {
    const float* x  = (const float*)d_in[0];
    const float* hs = (const float*)d_in[1];
    const float* cs = (const float*)d_in[2];
    const float* Wf = (const float*)d_in[3];
    const float* bF = (const float*)d_in[4];
    const float* Wi = (const float*)d_in[5];
    const float* bI = (const float*)d_in[6];
    const float* Wc = (const float*)d_in[7];
    const float* bC = (const float*)d_in[8];
    const float* Wo = (const float*)d_in[9];
    const float* bO = (const float*)d_in[10];
    float* out = (float*)d_out;

    __bf16* A  = (__bf16*)d_ws;                                   // 32 MiB
    __bf16* Wt = (__bf16*)((char*)d_ws + (size_t)BROWS * IH * 2); // 16 MiB

    pack_A<<<BROWS * IH / 2048, 256, 0, stream>>>(x, hs, A);
    pack_W<<<4 * 32 * 64, 256, 0, stream>>>(Wf, Wi, Wc, Wo, Wt);
    lstm_gemm<<<dim3(HDIM / BH, BROWS / BM), 256, 0, stream>>>(A, Wt, cs, bF, bI, bC, bO, out);
}